// Round 8
// baseline (431.432 us; speedup 1.0000x reference)
//
#include <hip/hip_runtime.h>

// Point2Voxel: scatter-mean of point features into a B x 64^3 voxel grid.
// Outputs (flat, in order): masked_pc[N*3], voxel_feats[B*V*32],
// voxel_counts[B*V], inst_flag[B]  -- all float32.
//
// Binning matches XLA's compiled arithmetic: `t / 0.05` canonicalized to
// `t * 20.0f` (separate f32 roundings, NO FMA -> contract(off) LOAD-BEARING).
// Evidence: R2 (f32 div) 2.36, R3 (f64 div) 2.80, R4 (mul) PASS 0.0039.
//
// R6 scheme: gather, not scatter. Per-voxel linked lists (atomicExch push)
// built in ws; gather writes every feats/counts byte EXACTLY once.
//
// R8/R9 PROBES: gather ~122us (ideal ~60), build ~43us (ideal ~8).
// R11: nt loads/stores -15.7us (449.9).
// R12 PROBE: gather counters: hbm 45%, VALUBusy 23%, occ 74%, traffic =
//   model. LATENCY-BOUND (dependent head[v] load, MLP~1, 32 generations).
// R13: 4-voxel G-strided batching (MLP=4): -24us (425.9). CONFIRMED.
//
// R14 (this round): push the same latency lever in BOTH kernels.
//  - gather: kVB 4->8 (MLP=8, generations 8->4).
//  - build: 4 points/thread -- pc as 3x f32x4 (48B contiguous), masked_pc
//    as 3x full-line f32x4 nt stores (kills partial-line stride-12 RMW),
//    bid as int4, and 4 independent atomicExch in flight (MLP=4 on the
//    ~900cy dependent atomic that feeds nxt).
// Arithmetic per point unchanged. Predict 425.9 -> 390-405. If <10us:
// latency levers exhausted -> nt-store BW probe or declare floor.

static constexpr int kNX  = 64;
static constexpr int kNYZ = 64 * 64;
static constexpr int kV   = 64 * 64 * 64;
static constexpr int kB   = 8;
static constexpr int kC   = 32;
static constexpr int kNV  = kB * kV;      // 2,097,152 voxels
static constexpr int kVB  = 8;            // voxels per gather thread
static constexpr int kG   = kNV / kVB;    // 262,144 (stride between them)

typedef float f32x4 __attribute__((ext_vector_type(4)));  // nt-able float4

// ---------------- fast path: linked-list gather ----------------

// Kernel A: 4 points per thread, vectorized IO, batched atomics.
__global__ void __launch_bounds__(256) p2v_build4(
    const float* __restrict__ pc, const int* __restrict__ bid,
    float* __restrict__ masked_pc, int* __restrict__ head,
    int* __restrict__ nxt, float* __restrict__ inst_flag, int n)
{
#pragma clang fp contract(off) reassociate(off)
  const float HALF     = (float)(0.5 * 64 * 0.05);  // 1.60000002384f
  const float INV_UNIT = 20.0f;                      // XLA: /0.05 -> *20.0f

  int t  = blockIdx.x * blockDim.x + threadIdx.x;
  int i0 = t * 4;
  if (i0 >= n) return;

  if (i0 + 4 <= n) {
    // ---- full quad: vector path ----
    // 12 floats = 3 x f32x4, 16B-aligned (offset 48t).
    const f32x4* pcv = (const f32x4*)(pc + (size_t)3 * i0);
    f32x4 A = pcv[0], Bv = pcv[1], Cv = pcv[2];
    float arr[12];
#pragma unroll
    for (int j = 0; j < 4; ++j) { arr[j] = A[j]; arr[4 + j] = Bv[j]; arr[8 + j] = Cv[j]; }

    const int4 b4 = *(const int4*)(bid + i0);
    int bv[4] = {b4.x, b4.y, b4.z, b4.w};

    bool valid[4];
    int  lin[4];
    float m[12];
#pragma unroll
    for (int j = 0; j < 4; ++j) {
      float x = arr[3 * j + 0];
      float y = arr[3 * j + 1];
      float z = arr[3 * j + 2];
      bool vj = (fabsf(x) <= HALF) && (fabsf(y) <= HALF) && (fabsf(z) <= HALF);
      valid[j] = vj;
      m[3 * j + 0] = vj ? x : 0.0f;
      m[3 * j + 1] = vj ? y : 0.0f;
      m[3 * j + 2] = vj ? z : 0.0f;
      float tx = x + HALF;
      float ty = y + HALF;
      float tz = z + HALF;
      int ix = (int)(tx * INV_UNIT);
      int iy = (int)(ty * INV_UNIT);
      int iz = (int)(tz * INV_UNIT);
      ix = min(max(ix, 0), kNX - 1);
      iy = min(max(iy, 0), kNX - 1);
      iz = min(max(iz, 0), kNX - 1);
      lin[j] = bv[j] * kV + ix * kNYZ + iy * kNX + iz;
    }

    // full-line vector nt stores (no partial-line RMW)
    f32x4 M0, M1, M2;
#pragma unroll
    for (int j = 0; j < 4; ++j) { M0[j] = m[j]; M1[j] = m[4 + j]; M2[j] = m[8 + j]; }
    f32x4* mp = (f32x4*)(masked_pc + (size_t)3 * i0);
    __builtin_nontemporal_store(M0, mp + 0);
    __builtin_nontemporal_store(M1, mp + 1);
    __builtin_nontemporal_store(M2, mp + 2);

    // 4 independent atomicExch in flight (MLP=4), then publish nxt.
    int old[4];
#pragma unroll
    for (int j = 0; j < 4; ++j)
      if (valid[j]) old[j] = atomicExch(head + lin[j], i0 + j);
#pragma unroll
    for (int j = 0; j < 4; ++j)
      if (valid[j]) __builtin_nontemporal_store(old[j], nxt + i0 + j);

    bool any = valid[0] | valid[1] | valid[2] | valid[3];
    if (any) {
      // batches rarely mix, but write each distinct flag present
#pragma unroll
      for (int j = 0; j < 4; ++j)
        if (valid[j]) inst_flag[bv[j]] = 1.0f;  // benign same-value race
    }
  } else {
    // ---- tail (n % 4 != 0): scalar per point ----
    for (int i = i0; i < n; ++i) {
      float x = pc[3 * i + 0];
      float y = pc[3 * i + 1];
      float z = pc[3 * i + 2];
      int   b = bid[i];
      bool valid = (fabsf(x) <= HALF) && (fabsf(y) <= HALF) && (fabsf(z) <= HALF);
      __builtin_nontemporal_store(valid ? x : 0.0f, masked_pc + 3 * i + 0);
      __builtin_nontemporal_store(valid ? y : 0.0f, masked_pc + 3 * i + 1);
      __builtin_nontemporal_store(valid ? z : 0.0f, masked_pc + 3 * i + 2);
      if (!valid) continue;
      int ix = (int)((x + HALF) * INV_UNIT);
      int iy = (int)((y + HALF) * INV_UNIT);
      int iz = (int)((z + HALF) * INV_UNIT);
      ix = min(max(ix, 0), kNX - 1);
      iy = min(max(iy, 0), kNX - 1);
      iz = min(max(iz, 0), kNX - 1);
      int lin = b * kV + ix * kNYZ + iy * kNX + iz;
      __builtin_nontemporal_store(atomicExch(head + lin, i), nxt + i);
      inst_flag[b] = 1.0f;
    }
  }
}

// Kernel B: gather, 8 voxels per thread (G-strided), 8 lanes per voxel slot,
// each lane owns 4 channels. 8 head loads issue together (MLP=8 on the
// dominant latency); per-voxel chain walk order unchanged. Per unrolled k,
// a wave still writes 8 consecutive voxels = 1KB contiguous.
__global__ void __launch_bounds__(256) p2v_gather8(
    const float* __restrict__ feat, const int* __restrict__ head,
    const int* __restrict__ nxt, float* __restrict__ voxel_feats,
    float* __restrict__ voxel_counts)
{
#pragma clang fp contract(off) reassociate(off)
  int gid = blockIdx.x * blockDim.x + threadIdx.x;  // < kG*8
  int q  = gid >> 3;
  int c4 = (gid & 7) * 4;
  if (q >= kG) return;

  int h0[kVB];
#pragma unroll
  for (int k = 0; k < kVB; ++k) h0[k] = head[q + k * kG];  // 8 loads in flight

#pragma unroll
  for (int k = 0; k < kVB; ++k) {
    int v = q + k * kG;
    f32x4 sum = (f32x4)(0.0f);
    int cnt = 0;
    int h = h0[k];
    while (h >= 0) {
      const f32x4 f = __builtin_nontemporal_load(
          (const f32x4*)(feat + (size_t)h * kC + c4));
      sum.x += f.x; sum.y += f.y; sum.z += f.z; sum.w += f.w;
      ++cnt;
      h = nxt[h];
    }

    if (cnt >= 2) {
      double dc = (double)cnt;  // IEEE f32-equivalent quotient via double
      sum.x = (float)((double)sum.x / dc);
      sum.y = (float)((double)sum.y / dc);
      sum.z = (float)((double)sum.z / dc);
      sum.w = (float)((double)sum.w / dc);
    }
    __builtin_nontemporal_store(sum,
                                (f32x4*)(voxel_feats + (size_t)v * kC + c4));
    if (c4 == 0) __builtin_nontemporal_store((float)cnt, voxel_counts + v);
  }
}

// ---------------- fallback path (ws too small): R4/R5 atomic scheme --------

__global__ void __launch_bounds__(256) p2v_main_fb(
    const float* __restrict__ pc, const float* __restrict__ feat,
    const int* __restrict__ bid, float* __restrict__ masked_pc,
    float* __restrict__ voxel_feats, float* __restrict__ voxel_counts,
    float* __restrict__ inst_flag, int n)
{
#pragma clang fp contract(off) reassociate(off)
  int i = blockIdx.x * blockDim.x + threadIdx.x;
  if (i >= n) return;
  const float HALF = (float)(0.5 * 64 * 0.05);
  const float INV_UNIT = 20.0f;
  float x = pc[3 * i + 0], y = pc[3 * i + 1], z = pc[3 * i + 2];
  bool valid = (fabsf(x) <= HALF) && (fabsf(y) <= HALF) && (fabsf(z) <= HALF);
  masked_pc[3 * i + 0] = valid ? x : 0.0f;
  masked_pc[3 * i + 1] = valid ? y : 0.0f;
  masked_pc[3 * i + 2] = valid ? z : 0.0f;
  if (!valid) return;
  int ix = (int)((x + HALF) * INV_UNIT);
  int iy = (int)((y + HALF) * INV_UNIT);
  int iz = (int)((z + HALF) * INV_UNIT);
  ix = min(max(ix, 0), kNX - 1);
  iy = min(max(iy, 0), kNX - 1);
  iz = min(max(iz, 0), kNX - 1);
  int b = bid[i];
  size_t lin = (size_t)b * kV + (size_t)(ix * kNYZ + iy * kNX + iz);
  atomicAdd(voxel_counts + lin, 1.0f);
  inst_flag[b] = 1.0f;
  float* dst = voxel_feats + lin * kC;
  const float* src = feat + (size_t)i * kC;
#pragma unroll
  for (int c = 0; c < kC; ++c) atomicAdd(dst + c, src[c]);
}

__global__ void __launch_bounds__(256) p2v_finalize_fb(
    float* __restrict__ voxel_feats, const float* __restrict__ voxel_counts)
{
#pragma clang fp contract(off) reassociate(off)
  int v = blockIdx.x * blockDim.x + threadIdx.x;
  if (v >= kB * kV) return;
  float c = voxel_counts[v];
  if (c >= 2.0f) {
    float* p = voxel_feats + (size_t)v * kC;
#pragma unroll
    for (int k = 0; k < kC; ++k) p[k] = (float)((double)p[k] / (double)c);
  }
}

// ---------------------------------------------------------------------------

extern "C" void kernel_launch(void* const* d_in, const int* in_sizes, int n_in,
                              void* d_out, int out_size, void* d_ws, size_t ws_size,
                              hipStream_t stream) {
  const float* pc   = (const float*)d_in[0];
  const float* feat = (const float*)d_in[1];
  const int*   bid  = (const int*)d_in[2];
  float* out = (float*)d_out;

  int n = in_sizes[0] / 3;

  float* masked_pc    = out;
  float* voxel_feats  = out + (size_t)3 * n;
  float* voxel_counts = voxel_feats + (size_t)kB * kV * kC;
  float* inst_flag    = voxel_counts + (size_t)kB * kV;

  const int block = 256;
  size_t need = (size_t)kB * kV * sizeof(int) + (size_t)n * sizeof(int);

  if (ws_size >= need) {
    // Fast path: linked-list gather.
    int* head = (int*)d_ws;              // B*V ints (8 MB)
    int* nxt  = head + (size_t)kB * kV;  // n ints (4 MB)

    (void)hipMemsetAsync(head, 0xFF, (size_t)kB * kV * sizeof(int), stream);
    (void)hipMemsetAsync(inst_flag, 0, kB * sizeof(float), stream);

    int nq = (n + 3) / 4;  // point-quads
    p2v_build4<<<(nq + block - 1) / block, block, 0, stream>>>(
        pc, bid, masked_pc, head, nxt, inst_flag, n);

    long long ng = (long long)kG * 8;  // 8 lanes x NV/8 voxel-octs
    p2v_gather8<<<(int)((ng + block - 1) / block), block, 0, stream>>>(
        feat, head, nxt, voxel_feats, voxel_counts);
  } else {
    // Fallback: proven R5 atomic scheme (needs no ws).
    size_t tail_floats = (size_t)kB * kV * kC + (size_t)kB * kV + kB;
    (void)hipMemsetAsync(voxel_feats, 0, tail_floats * sizeof(float), stream);
    p2v_main_fb<<<(n + block - 1) / block, block, 0, stream>>>(
        pc, feat, bid, masked_pc, voxel_feats, voxel_counts, inst_flag, n);
    int nv = kB * kV;
    p2v_finalize_fb<<<(nv + block - 1) / block, block, 0, stream>>>(
        voxel_feats, voxel_counts);
  }
}

// Round 9
// 427.007 us; speedup vs baseline: 1.0104x; 1.0104x over previous
//
#include <hip/hip_runtime.h>

// Point2Voxel: scatter-mean of point features into a B x 64^3 voxel grid.
// Outputs (flat, in order): masked_pc[N*3], voxel_feats[B*V*32],
// voxel_counts[B*V], inst_flag[B]  -- all float32.
//
// Binning matches XLA's compiled arithmetic: `t / 0.05` canonicalized to
// `t * 20.0f` (separate f32 roundings, NO FMA -> contract(off) LOAD-BEARING).
// Evidence: R2 (f32 div) 2.36, R3 (f64 div) 2.80, R4 (mul) PASS 0.0039.
//
// R6 scheme: gather, not scatter. Per-voxel linked lists (atomicExch push)
// built in ws; gather writes every feats/counts byte EXACTLY once.
//
// R8/R9 PROBES: gather ~122us (ideal ~60), build ~43us (ideal ~8).
// R11: nt loads/stores -15.7us (449.9).
// R12 PROBE: gather hbm 45%, VALUBusy 23%, occ 74%, traffic = model ->
//   LATENCY-BOUND (dependent head[v] load, MLP~1, 32 generations).
// R13: 4-voxel G-strided head batching (MLP=4): -24us (425.9). CONFIRMED.
// R14 FAILED (+5.5): kVB=8 + build4 vectorize/atomic-batch. Lessons:
//   head-MLP lever exhausted at 4; build residual ~= atomicExch transaction
//   throughput (~8/cy device-wide), batching can't compress it.
//
// R15 (this round): revert to R13 base; attack the one un-attacked latency
// component: the SERIAL CHAIN WALK. R13 walks each voxel's chain to
// completion (dependent nxt/feat loads, MLP=1 within a chain; center voxels
// have chains 3-8 -> 2-5k cy serialized tails). Lockstep interleaved walk:
// advance all 4 chains per while-iteration -> up to 4 feat + 4 nxt loads in
// flight. Per-chain accumulation order UNCHANGED -> outputs bit-identical.
// Predict 425.9 -> 405-418. If |delta|<6us: chain latency already TLP-hidden
// -> declare structural floor (atomic throughput + scatter/store floor).

static constexpr int kNX  = 64;
static constexpr int kNYZ = 64 * 64;
static constexpr int kV   = 64 * 64 * 64;
static constexpr int kB   = 8;
static constexpr int kC   = 32;
static constexpr int kNV  = kB * kV;      // 2,097,152 voxels
static constexpr int kVB  = 4;            // voxels per gather thread (R13 best)
static constexpr int kG   = kNV / kVB;    // 524,288 (stride between them)

typedef float f32x4 __attribute__((ext_vector_type(4)));  // nt-able float4

// ---------------- fast path: linked-list gather ----------------

// Kernel A: per-point (R11/R13 proven form). masked_pc, validity, list push.
__global__ void __launch_bounds__(256) p2v_build(
    const float* __restrict__ pc, const int* __restrict__ bid,
    float* __restrict__ masked_pc, int* __restrict__ head,
    int* __restrict__ nxt, float* __restrict__ inst_flag, int n)
{
#pragma clang fp contract(off) reassociate(off)
  int i = blockIdx.x * blockDim.x + threadIdx.x;
  if (i >= n) return;

  const float HALF     = (float)(0.5 * 64 * 0.05);  // 1.60000002384f
  const float INV_UNIT = 20.0f;                      // XLA: /0.05 -> *20.0f

  float x = pc[3 * i + 0];
  float y = pc[3 * i + 1];
  float z = pc[3 * i + 2];
  int   b = bid[i];

  bool valid = (fabsf(x) <= HALF) && (fabsf(y) <= HALF) && (fabsf(z) <= HALF);

  __builtin_nontemporal_store(valid ? x : 0.0f, masked_pc + 3 * i + 0);
  __builtin_nontemporal_store(valid ? y : 0.0f, masked_pc + 3 * i + 1);
  __builtin_nontemporal_store(valid ? z : 0.0f, masked_pc + 3 * i + 2);

  if (!valid) return;

  float tx = x + HALF;
  float ty = y + HALF;
  float tz = z + HALF;
  int ix = (int)(tx * INV_UNIT);
  int iy = (int)(ty * INV_UNIT);
  int iz = (int)(tz * INV_UNIT);
  ix = min(max(ix, 0), kNX - 1);
  iy = min(max(iy, 0), kNX - 1);
  iz = min(max(iz, 0), kNX - 1);

  int lin = b * kV + ix * kNYZ + iy * kNX + iz;
  // Gather runs in a later kernel (full barrier between) -> nt store of nxt
  // is safe relative to the atomicExch publish.
  __builtin_nontemporal_store(atomicExch(head + lin, i), nxt + i);
  inst_flag[b] = 1.0f;  // benign race: same value
}

// Kernel B: gather, 4 voxels per thread (G-strided), 8 lanes per voxel slot,
// each lane owns 4 channels. Head loads batched (MLP=4, R13); chain walks
// advanced in LOCKSTEP so chase-step loads of different chains overlap
// (R15). Per-chain walk order unchanged -> bit-identical accumulation.
__global__ void __launch_bounds__(256) p2v_gather4(
    const float* __restrict__ feat, const int* __restrict__ head,
    const int* __restrict__ nxt, float* __restrict__ voxel_feats,
    float* __restrict__ voxel_counts)
{
#pragma clang fp contract(off) reassociate(off)
  int gid = blockIdx.x * blockDim.x + threadIdx.x;  // < kG*8
  int q  = gid >> 3;
  int c4 = (gid & 7) * 4;
  if (q >= kG) return;

  int h[kVB];
#pragma unroll
  for (int k = 0; k < kVB; ++k) h[k] = head[q + k * kG];  // 4 loads in flight

  f32x4 sum[kVB];
  int   cnt[kVB];
#pragma unroll
  for (int k = 0; k < kVB; ++k) { sum[k] = (f32x4)(0.0f); cnt[k] = 0; }

  // Lockstep walk: one iteration advances every live chain by one step.
  // Loads for distinct k are independent -> up to 4 feat + 4 nxt loads in
  // flight per iteration (vs MLP=1 of a serial per-chain walk).
  while ((h[0] >= 0) | (h[1] >= 0) | (h[2] >= 0) | (h[3] >= 0)) {
#pragma unroll
    for (int k = 0; k < kVB; ++k) {
      int hk = h[k];
      if (hk >= 0) {
        const f32x4 f = __builtin_nontemporal_load(
            (const f32x4*)(feat + (size_t)hk * kC + c4));
        sum[k].x += f.x; sum[k].y += f.y; sum[k].z += f.z; sum[k].w += f.w;
        ++cnt[k];
        h[k] = nxt[hk];
      }
    }
  }

#pragma unroll
  for (int k = 0; k < kVB; ++k) {
    int v = q + k * kG;
    f32x4 s = sum[k];
    int   c = cnt[k];
    if (c >= 2) {
      double dc = (double)c;  // IEEE f32-equivalent quotient via double
      s.x = (float)((double)s.x / dc);
      s.y = (float)((double)s.y / dc);
      s.z = (float)((double)s.z / dc);
      s.w = (float)((double)s.w / dc);
    }
    __builtin_nontemporal_store(s, (f32x4*)(voxel_feats + (size_t)v * kC + c4));
    if (c4 == 0) __builtin_nontemporal_store((float)c, voxel_counts + v);
  }
}

// ---------------- fallback path (ws too small): R4/R5 atomic scheme --------

__global__ void __launch_bounds__(256) p2v_main_fb(
    const float* __restrict__ pc, const float* __restrict__ feat,
    const int* __restrict__ bid, float* __restrict__ masked_pc,
    float* __restrict__ voxel_feats, float* __restrict__ voxel_counts,
    float* __restrict__ inst_flag, int n)
{
#pragma clang fp contract(off) reassociate(off)
  int i = blockIdx.x * blockDim.x + threadIdx.x;
  if (i >= n) return;
  const float HALF = (float)(0.5 * 64 * 0.05);
  const float INV_UNIT = 20.0f;
  float x = pc[3 * i + 0], y = pc[3 * i + 1], z = pc[3 * i + 2];
  bool valid = (fabsf(x) <= HALF) && (fabsf(y) <= HALF) && (fabsf(z) <= HALF);
  masked_pc[3 * i + 0] = valid ? x : 0.0f;
  masked_pc[3 * i + 1] = valid ? y : 0.0f;
  masked_pc[3 * i + 2] = valid ? z : 0.0f;
  if (!valid) return;
  int ix = (int)((x + HALF) * INV_UNIT);
  int iy = (int)((y + HALF) * INV_UNIT);
  int iz = (int)((z + HALF) * INV_UNIT);
  ix = min(max(ix, 0), kNX - 1);
  iy = min(max(iy, 0), kNX - 1);
  iz = min(max(iz, 0), kNX - 1);
  int b = bid[i];
  size_t lin = (size_t)b * kV + (size_t)(ix * kNYZ + iy * kNX + iz);
  atomicAdd(voxel_counts + lin, 1.0f);
  inst_flag[b] = 1.0f;
  float* dst = voxel_feats + lin * kC;
  const float* src = feat + (size_t)i * kC;
#pragma unroll
  for (int c = 0; c < kC; ++c) atomicAdd(dst + c, src[c]);
}

__global__ void __launch_bounds__(256) p2v_finalize_fb(
    float* __restrict__ voxel_feats, const float* __restrict__ voxel_counts)
{
#pragma clang fp contract(off) reassociate(off)
  int v = blockIdx.x * blockDim.x + threadIdx.x;
  if (v >= kB * kV) return;
  float c = voxel_counts[v];
  if (c >= 2.0f) {
    float* p = voxel_feats + (size_t)v * kC;
#pragma unroll
    for (int k = 0; k < kC; ++k) p[k] = (float)((double)p[k] / (double)c);
  }
}

// ---------------------------------------------------------------------------

extern "C" void kernel_launch(void* const* d_in, const int* in_sizes, int n_in,
                              void* d_out, int out_size, void* d_ws, size_t ws_size,
                              hipStream_t stream) {
  const float* pc   = (const float*)d_in[0];
  const float* feat = (const float*)d_in[1];
  const int*   bid  = (const int*)d_in[2];
  float* out = (float*)d_out;

  int n = in_sizes[0] / 3;

  float* masked_pc    = out;
  float* voxel_feats  = out + (size_t)3 * n;
  float* voxel_counts = voxel_feats + (size_t)kB * kV * kC;
  float* inst_flag    = voxel_counts + (size_t)kB * kV;

  const int block = 256;
  size_t need = (size_t)kB * kV * sizeof(int) + (size_t)n * sizeof(int);

  if (ws_size >= need) {
    // Fast path: linked-list gather.
    int* head = (int*)d_ws;              // B*V ints (8 MB)
    int* nxt  = head + (size_t)kB * kV;  // n ints (4 MB)

    (void)hipMemsetAsync(head, 0xFF, (size_t)kB * kV * sizeof(int), stream);
    (void)hipMemsetAsync(inst_flag, 0, kB * sizeof(float), stream);

    p2v_build<<<(n + block - 1) / block, block, 0, stream>>>(
        pc, bid, masked_pc, head, nxt, inst_flag, n);

    long long ng = (long long)kG * 8;  // 8 lanes x NV/4 voxel-quads
    p2v_gather4<<<(int)((ng + block - 1) / block), block, 0, stream>>>(
        feat, head, nxt, voxel_feats, voxel_counts);
  } else {
    // Fallback: proven R5 atomic scheme (needs no ws).
    size_t tail_floats = (size_t)kB * kV * kC + (size_t)kB * kV + kB;
    (void)hipMemsetAsync(voxel_feats, 0, tail_floats * sizeof(float), stream);
    p2v_main_fb<<<(n + block - 1) / block, block, 0, stream>>>(
        pc, feat, bid, masked_pc, voxel_feats, voxel_counts, inst_flag, n);
    int nv = kB * kV;
    p2v_finalize_fb<<<(nv + block - 1) / block, block, 0, stream>>>(
        voxel_feats, voxel_counts);
  }
}